// Round 6
// baseline (140.607 us; speedup 1.0000x reference)
//
#include <hip/hip_runtime.h>

// Problem constants (match reference)
#define BB 128
#define SS 8192
#define VV 128000

// Output element offsets (flat float32 view of d_out, tuple return order)
#define OFF_TOK 0
#define OFF_LTI (OFF_TOK + BB)
#define OFF_MASK (OFF_LTI + BB)            // 256
#define OFF_GEN (OFF_MASK + BB * SS)       // 1048832
#define OFF_STR (OFF_GEN + BB * SS)        // 2097408
#define OFF_GI  (OFF_STR + BB * SS)        // 3145984
#define OFF_CNT (OFF_GI + BB)              // 3146112

// Native clang vectors — __builtin_nontemporal_load needs ext_vector types
typedef float f32x4 __attribute__((ext_vector_type(4)));
typedef int   i32x4 __attribute__((ext_vector_type(4)));

// Cache policy (measured r2-r4): NT loads + PLAIN stores (NT/NT=146, pl/pl=148, NT/pl=138).
// This round: persistent balanced grid — 2048 blocks = exactly 8 blocks/CU,
// block-strided chunk assignment, zero occupancy-wave tail (was 0.33/1.16-wave
// tails at 4769/2385 blocks). Work = 19072 chunk-units = 2048*9 + 640.
#define CHUNKS_S_PER 262144            // BB*SS/4 chunks per S-region
#define CHUNKS_S_ALL 786432            // 3 S-regions (multiple of 256 -> uniform branches)
#define CB_TOTAL     19072             // total 256-chunk units (4,882,432 chunks / 256)
#define GRID         2048              // 8 blocks/CU exactly

__global__ void __launch_bounds__(256)
k_fused(const int* __restrict__ tokens,
        const int* __restrict__ lti_in,
        const float* __restrict__ mask_in,
        const int* __restrict__ gen_in,
        const int* __restrict__ str_in,
        const int* __restrict__ gi_in,
        const int* __restrict__ cnt_in,
        float* __restrict__ out)
{
    const int bid = blockIdx.x;
    const int tid = threadIdx.x;

    // tiny (B,) outputs: tokens, lti+1 clamped, gi+1 clamped — one block only
    if (bid == 0 && tid < BB) {
        out[OFF_TOK + tid] = (float)tokens[tid];
        out[OFF_LTI + tid] = (float)min(lti_in[tid] + 1, SS - 1);
        out[OFF_GI  + tid] = (float)min(gi_in[tid] + 1, SS - 1);
    }

    #pragma unroll
    for (int k = 0; k < 10; ++k) {
        const int cb = k * GRID + bid;        // chunk-unit index (256 chunks each)
        if (cb >= CB_TOTAL) break;            // block-uniform; only k==9 can trigger
        const int c = cb * 256 + tid;         // global float4-chunk index

        if (c < CHUNKS_S_ALL) {
            // ---- attention_mask / generated_tokens / generated_tokens_streaming ----
            const int    region = c >> 18;             // 0=mask 1=gen 2=str (block-uniform)
            const int    cr     = c & (CHUNKS_S_PER - 1);
            const int    b      = cr >> 11;            // 2048 chunks per S-row
            const int    s0     = (cr & 2047) << 2;    // first s covered by chunk
            const size_t e      = (size_t)cr << 2;     // element offset within region
            if (region == 0) {
                f32x4 m = __builtin_nontemporal_load((const f32x4*)(mask_in + e));
                const int lti_new = min(lti_in[b] + 1, SS - 1);   // L1-hit broadcast
                if ((unsigned)(lti_new - s0) < 4u)
                    m[lti_new - s0] = 1.0f;
                *(f32x4*)(out + OFF_MASK + e) = m;     // plain store
            } else {
                const int* src  = (region == 1) ? gen_in : str_in;
                float*     dstp = out + ((region == 1) ? OFF_GEN : OFF_STR);
                i32x4 g = __builtin_nontemporal_load((const i32x4*)(src + e));
                f32x4 go = { (float)g[0], (float)g[1], (float)g[2], (float)g[3] };
                const int gi_old = gi_in[b];           // scatter at PRE-increment idx
                if ((unsigned)(gi_old - s0) < 4u)
                    go[gi_old - s0] = (float)tokens[b];
                *(f32x4*)(dstp + e) = go;              // plain store
            }
        } else {
            // ---- token_count: copy int->float, +1 at tokens[b] per row ----
            const int    cr = c - CHUNKS_S_ALL;
            const int    b  = cr / 32000;              // compiler magic-mul
            const int    v0 = (cr - b * 32000) << 2;   // first vocab idx of chunk
            const size_t e  = (size_t)cr << 2;
            i32x4 cc = __builtin_nontemporal_load((const i32x4*)(cnt_in + e));
            f32x4 co = { (float)cc[0], (float)cc[1], (float)cc[2], (float)cc[3] };
            const int tok = tokens[b];                 // L1-hit broadcast
            if ((unsigned)(tok - v0) < 4u)
                co[tok - v0] += 1.0f;
            *(f32x4*)(out + OFF_CNT + e) = co;         // plain store
        }
    }
}

extern "C" void kernel_launch(void* const* d_in, const int* in_sizes, int n_in,
                              void* d_out, int out_size, void* d_ws, size_t ws_size,
                              hipStream_t stream) {
    const int*   tokens = (const int*)  d_in[0];
    const int*   lti    = (const int*)  d_in[1];
    const float* mask   = (const float*)d_in[2];
    const int*   gen    = (const int*)  d_in[3];
    const int*   strm   = (const int*)  d_in[4];
    const int*   gi     = (const int*)  d_in[5];
    const int*   cnt    = (const int*)  d_in[6];
    float* out = (float*)d_out;

    k_fused<<<dim3(GRID), dim3(256), 0, stream>>>(
        tokens, lti, mask, gen, strm, gi, cnt, out);
}